// Round 13
// baseline (414.083 us; speedup 1.0000x reference)
//
#include <hip/hip_runtime.h>

#define Bsz 256
#define Usz 64
#define CVsz 61
#define INsz 3
#define Hsz 1024
#define Gsz 4096
#define NGsz 20
#define NAGsz 10
#define IN2sz 2112

typedef __attribute__((ext_vector_type(8))) short bf16x8;
typedef __attribute__((ext_vector_type(4))) float f32x4;
typedef __attribute__((ext_vector_type(4))) unsigned int u32x4;

__device__ __forceinline__ unsigned int pk2(float x, float y) {
  unsigned int a = __float_as_uint(x), b = __float_as_uint(y);
  return ((a + 0x8000u) >> 16) | ((b + 0x8000u) & 0xffff0000u);
}
__device__ __forceinline__ unsigned short bf1(float x) {
  return (unsigned short)((__float_as_uint(x) + 0x8000u) >> 16);
}
__device__ __forceinline__ bf16x8 pkb(float4 lo, float4 hi) {
  union { u32x4 u; bf16x8 b; } cv;
  cv.u = (u32x4){pk2(lo.x, lo.y), pk2(lo.z, lo.w), pk2(hi.x, hi.y), pk2(hi.z, hi.w)};
  return cv.b;
}
__device__ __forceinline__ float sigf(float x) { return 1.f / (1.f + __expf(-x)); }

struct GemmP {
  const unsigned short* X1; int ldx1; int nc1;   // bf16 activation part 1
  const unsigned short* Hst;                     // bf16 h-state (2 dirs), ld=Hsz
  const float* Wf1; const float* Wb1; int ldw1;  // f32 Wih per dir
  const float* Wf2; const float* Wb2;            // f32 Whh per dir, ld=Hsz
  const float* bihf; const float* bhhf; const float* bihb; const float* bhhb;
  float* gout;
  int ksplit; int totc; int ndir; int nW; int ldo;
};

// C[m][n] = sum_k A[m][k] * W[n][k] (+bias on slice 0). No LDS, no barriers:
// 64x64 block tile, 4 waves 2x2 (wave 32x32 = 2x2 frags), BK=32/iter, 4 MFMA/iter.
// Small tile -> 4x grid -> 32 waves/CU; independent waves hide the serialized
// per-wave load latency the compiler insists on (r7/r9/r10 evidence).
__global__ __launch_bounds__(256, 6) void gemm_k(GemmP p) {
  int t = threadIdx.x;
  int n0 = blockIdx.x * 64, m0 = blockIdx.y * 64;
  int z = blockIdx.z;
  int d = (p.ndir == 2) ? (z & 1) : 0;
  int s = (p.ndir == 2) ? (z >> 1) : z;
  const float* Wih = d ? p.Wb1 : p.Wf1;
  const float* Whh = d ? p.Wb2 : p.Wf2;
  const unsigned short* Hx = p.Hst + (size_t)d * Bsz * Hsz;
  int c0 = (p.totc * s) / p.ksplit, c1 = (p.totc * (s + 1)) / p.ksplit;
  int wv = t >> 6, ln = t & 63;
  int wr = wv >> 1, wc = wv & 1;
  int fr = ln & 15, kg = ln >> 4;

  int rA[2], rB[2];
#pragma unroll
  for (int i = 0; i < 2; i++) rA[i] = m0 + wr * 32 + i * 16 + fr;
#pragma unroll
  for (int j = 0; j < 2; j++) {
    int r = n0 + wc * 32 + j * 16 + fr;
    rB[j] = (r < p.nW) ? r : (p.nW - 1);
  }

  f32x4 acc[2][2];
#pragma unroll
  for (int i = 0; i < 2; i++)
#pragma unroll
    for (int j = 0; j < 2; j++) acc[i][j] = (f32x4){0.f, 0.f, 0.f, 0.f};

  // region 1: X1 (bf16, ldx1) x Wih (f32, ldw1)
  int e1 = (c1 < p.nc1) ? c1 : p.nc1;
#pragma unroll 2
  for (int c = c0; c < e1; ++c) {
    int kx = c * 32 + kg * 8;
    bf16x8 av[2], bv[2];
#pragma unroll
    for (int i = 0; i < 2; i++)
      av[i] = *(const bf16x8*)(p.X1 + (size_t)rA[i] * p.ldx1 + kx);
#pragma unroll
    for (int j = 0; j < 2; j++) {
      const float* wp = Wih + (size_t)rB[j] * p.ldw1 + kx;
      bv[j] = pkb(*(const float4*)wp, *(const float4*)(wp + 4));
    }
#pragma unroll
    for (int i = 0; i < 2; i++)
#pragma unroll
      for (int j = 0; j < 2; j++)
        acc[i][j] = __builtin_amdgcn_mfma_f32_16x16x32_bf16(av[i], bv[j], acc[i][j], 0, 0, 0);
  }

  // region 2: Hx (bf16, ld=Hsz) x Whh (f32, ld=Hsz)
  int s2 = (c0 > p.nc1) ? c0 : p.nc1;
#pragma unroll 2
  for (int c = s2; c < c1; ++c) {
    int kx = (c - p.nc1) * 32 + kg * 8;
    bf16x8 av[2], bv[2];
#pragma unroll
    for (int i = 0; i < 2; i++)
      av[i] = *(const bf16x8*)(Hx + (size_t)rA[i] * Hsz + kx);
#pragma unroll
    for (int j = 0; j < 2; j++) {
      const float* wp = Whh + (size_t)rB[j] * Hsz + kx;
      bv[j] = pkb(*(const float4*)wp, *(const float4*)(wp + 4));
    }
#pragma unroll
    for (int i = 0; i < 2; i++)
#pragma unroll
      for (int j = 0; j < 2; j++)
        acc[i][j] = __builtin_amdgcn_mfma_f32_16x16x32_bf16(av[i], bv[j], acc[i][j], 0, 0, 0);
  }

  const float* bi = d ? p.bihb : p.bihf;
  const float* bh = d ? p.bhhb : p.bhhf;
  float* outp = p.gout + (size_t)(s * p.ndir + d) * Bsz * p.ldo;
#pragma unroll
  for (int i = 0; i < 2; i++) {
#pragma unroll
    for (int j = 0; j < 2; j++) {
      int col = n0 + wc * 32 + j * 16 + fr;
      float bias = 0.f;
      if (p.bihf && s == 0) bias = bi[col] + bh[col];
#pragma unroll
      for (int r = 0; r < 2 * 2; r++) {
        int row = m0 + wr * 32 + i * 16 + kg * 4 + (r & 3);
        if (r < 4)
          outp[(size_t)row * p.ldo + col] = acc[i][j][r] + bias;
      }
    }
  }
}

__global__ __launch_bounds__(256) void prep_x1b(const float* inp, const float* oldw, unsigned short* x1b) {
  int idx = blockIdx.x * 256 + threadIdx.x;  // 256*64
  int m = idx >> 6, k = idx & 63;
  float v = (k < INsz) ? inp[m * INsz + k] : oldw[m * CVsz + (k - INsz)];
  x1b[idx] = bf1(v);
}

__global__ __launch_bounds__(256) void cvt_h(const float* h, unsigned short* hb, int n) {
  int idx = blockIdx.x * 256 + threadIdx.x;
  if (idx < n) hb[idx] = bf1(h[idx]);
}

__global__ __launch_bounds__(256) void cell_k(const float* gates, int ksplit,
    const float* cin, float* hout, float* cout,
    unsigned short* db1, int ld1, int off1, unsigned short* db2, int ld2, int off2) {
  int idx = blockIdx.x * 256 + threadIdx.x;  // [0, 2*B*H)
  int j = idx & (Hsz - 1);
  int m = (idx >> 10) & 255;
  int d = idx >> 18;
  size_t base = ((size_t)d * Bsz + m) * Gsz + j;
  float gi = 0.f, gf = 0.f, gg = 0.f, go = 0.f;
  for (int s = 0; s < ksplit; ++s) {
    const float* gp = gates + (size_t)s * 2 * Bsz * Gsz + base;
    gi += gp[0]; gf += gp[1024]; gg += gp[2048]; go += gp[3072];
  }
  float c = cin[((size_t)d * Bsz + m) * Hsz + j];
  float cn = sigf(gf) * c + sigf(gi) * tanhf(gg);
  float hn = sigf(go) * tanhf(cn);
  hout[((size_t)d * Bsz + m) * Hsz + j] = hn;
  cout[((size_t)d * Bsz + m) * Hsz + j] = cn;
  unsigned short hb = bf1(hn);
  db1[(size_t)m * ld1 + off1 + d * Hsz + j] = hb;
  if (db2) db2[(size_t)m * ld2 + off2 + d * Hsz + j] = hb;
}

// Reduce win-projection partials, compute abk/k_t/phi/win, scatter bf16 into x2b.
__global__ __launch_bounds__(128) void win_fin(const float* winp, int ks,
    const float* bwin, const float* oldk, const float* inp, const float* cvec,
    const int* tl, unsigned short* x2b, float* ophi, float* owin, float* okt) {
  int m = blockIdx.x, t = threadIdx.x, wv = t >> 6, ln = t & 63;
  __shared__ float abk[30];
  __shared__ float phis[Usz];
  __shared__ float wpart[2][CVsz];
  if (t < 30) {
    float s = bwin[t];
    for (int q = 0; q < ks; ++q) s += winp[((size_t)q * Bsz + m) * 128 + t];
    abk[t] = __expf(s);
  }
  __syncthreads();
  if (t < NAGsz) {
    float kt = oldk[m * NAGsz + t] + abk[20 + t];
    abk[20 + t] = kt;
    okt[m * NAGsz + t] = kt;
  }
  __syncthreads();
  if (t < Usz) {
    float scale = 64.f / (float)tl[0];
    float ph = 0.f;
#pragma unroll
    for (int q = 0; q < NAGsz; ++q) {
      float dk = abk[20 + q] - (float)(t + 1);
      ph += abk[q] * __expf(-abk[10 + q] * dk * dk);
    }
    ph *= scale;
    phis[t] = ph;
    ophi[m * Usz + t] = ph;
  }
  __syncthreads();
  if (ln < CVsz) {
    float w = 0.f;
    const float* cv = cvec + (size_t)m * Usz * CVsz + (size_t)wv * 32 * CVsz + ln;
#pragma unroll
    for (int u = 0; u < 32; ++u) w += phis[wv * 32 + u] * cv[u * CVsz];
    wpart[wv][ln] = w;
  }
  __syncthreads();
  if (t < CVsz) {
    float w = wpart[0][t] + wpart[1][t];
    owin[m * CVsz + t] = w;
    x2b[(size_t)m * IN2sz + 2048 + INsz + t] = bf1(w);
  }
  if (t < INsz) x2b[(size_t)m * IN2sz + 2048 + t] = bf1(inp[m * INsz + t]);
}

__global__ __launch_bounds__(128) void mdn_fin(const float* part, int ks, const float* bm, float* out) {
  int m = blockIdx.x, t = threadIdx.x;
  __shared__ float y[121];
  if (t < 121) {
    float s = bm[t];
    for (int q = 0; q < ks; ++q) s += part[((size_t)q * Bsz + m) * 128 + t];
    y[t] = s;
  }
  __syncthreads();
  if (t == 0) out[m] = sigf(y[0]);
  if (t < NGsz) {
    float mx = -1e30f;
    for (int q = 0; q < NGsz; q++) mx = fmaxf(mx, y[1 + q]);
    float se = 0.f;
    for (int q = 0; q < NGsz; q++) se += __expf(y[1 + q] - mx);
    out[256   + m * NGsz + t] = __expf(y[1 + t] - mx) / se;  // pi
    out[5376  + m * NGsz + t] = y[21 + t];                   // mu1
    out[10496 + m * NGsz + t] = y[41 + t];                   // mu2
    out[15616 + m * NGsz + t] = __expf(y[61 + t]);           // exp(s1)
    out[20736 + m * NGsz + t] = __expf(y[81 + t]);           // exp(s2)
    out[25856 + m * NGsz + t] = tanhf(y[101 + t]);           // tanh(rho)
  }
}

extern "C" void kernel_launch(void* const* d_in, const int* in_sizes, int n_in,
                              void* d_out, int out_size, void* d_ws, size_t ws_size,
                              hipStream_t stream) {
  (void)in_sizes; (void)n_in; (void)out_size;
  const float* inp  = (const float*)d_in[0];
  const float* cvec = (const float*)d_in[1];
  const float* oldk = (const float*)d_in[2];
  const float* oldw = (const float*)d_in[3];
  const float* h1   = (const float*)d_in[4];
  const float* c1   = (const float*)d_in[5];
  const float* h2   = (const float*)d_in[6];
  const float* c2   = (const float*)d_in[7];
  const int*   tl   = (const int*)d_in[8];
  float* out = (float*)d_out;
  float* ws  = (float*)d_ws;

  size_t fixed_f = (size_t)524288 + 524288 + 8192 + 262144 + 262144 + 270336 + 524288;
  int ks2 = 4;
  while (ks2 > 1 && (fixed_f + (size_t)ks2 * 2 * 1048576) * 4 > ws_size) ks2 >>= 1;
  int ks1 = 4;

  float* ws_g    = ws;                     // ks2 * 2 * 1048576 f32 partials
  float* ws_mdn  = ws_g + (size_t)ks2 * 2 * 1048576;  // 16x256x128
  float* ws_winp = ws_mdn + 524288;        // 16x256x128
  float* bstart  = ws_winp + 524288;
  unsigned short* x1b  = (unsigned short*)bstart;          // 16384
  unsigned short* h1b  = x1b + 16384;                      // 524288
  unsigned short* h2b  = h1b + 524288;                     // 524288
  unsigned short* x2b  = h2b + 524288;                     // 540672
  unsigned short* catb = x2b + 540672;                     // 1048576

  prep_x1b<<<64, 256, 0, stream>>>(inp, oldw, x1b);
  cvt_h<<<2048, 256, 0, stream>>>(h1, h1b, 524288);
  cvt_h<<<2048, 256, 0, stream>>>(h2, h2b, 524288);

  GemmP g1{};
  g1.X1 = x1b; g1.ldx1 = 64; g1.nc1 = 2;
  g1.Hst = h1b;
  g1.Wf1 = (const float*)d_in[9];  g1.Wb1 = (const float*)d_in[13]; g1.ldw1 = 64;
  g1.Wf2 = (const float*)d_in[10]; g1.Wb2 = (const float*)d_in[14];
  g1.bihf = (const float*)d_in[11]; g1.bhhf = (const float*)d_in[12];
  g1.bihb = (const float*)d_in[15]; g1.bhhb = (const float*)d_in[16];
  g1.gout = ws_g; g1.ksplit = ks1; g1.totc = 34; g1.ndir = 2; g1.nW = 4096; g1.ldo = 4096;
  gemm_k<<<dim3(64, 4, 2 * ks1), 256, 0, stream>>>(g1);

  cell_k<<<2048, 256, 0, stream>>>(ws_g, ks1, c1, out + 65536, out + 589824,
                                   x2b, IN2sz, 0, catb, 4096, 0);

  // win projection: A = x2b[:, :2048] (bf16), B = W_win f32 [30,2048]
  GemmP gw{};
  gw.X1 = x2b; gw.ldx1 = IN2sz; gw.nc1 = 64;
  gw.Hst = x2b;
  gw.Wf1 = (const float*)d_in[25]; gw.Wb1 = (const float*)d_in[25]; gw.ldw1 = 2048;
  gw.Wf2 = (const float*)d_in[25]; gw.Wb2 = (const float*)d_in[25];
  gw.bihf = nullptr; gw.bhhf = nullptr; gw.bihb = nullptr; gw.bhhb = nullptr;
  gw.gout = ws_winp; gw.ksplit = 16; gw.totc = 64; gw.ndir = 1; gw.nW = 30; gw.ldo = 128;
  gemm_k<<<dim3(1, 4, 16), 256, 0, stream>>>(gw);

  win_fin<<<256, 128, 0, stream>>>(ws_winp, 16, (const float*)d_in[26],
                                   oldk, inp, cvec, tl, x2b,
                                   out + 30976, out + 47360, out + 62976);

  GemmP g2{};
  g2.X1 = x2b; g2.ldx1 = IN2sz; g2.nc1 = 66;
  g2.Hst = h2b;
  g2.Wf1 = (const float*)d_in[17]; g2.Wb1 = (const float*)d_in[21]; g2.ldw1 = IN2sz;
  g2.Wf2 = (const float*)d_in[18]; g2.Wb2 = (const float*)d_in[22];
  g2.bihf = (const float*)d_in[19]; g2.bhhf = (const float*)d_in[20];
  g2.bihb = (const float*)d_in[23]; g2.bhhb = (const float*)d_in[24];
  g2.gout = ws_g; g2.ksplit = ks2; g2.totc = 98; g2.ndir = 2; g2.nW = 4096; g2.ldo = 4096;
  gemm_k<<<dim3(64, 4, 2 * ks2), 256, 0, stream>>>(g2);

  cell_k<<<2048, 256, 0, stream>>>(ws_g, ks2, c2, out + 1114112, out + 1638400,
                                   catb, 4096, 2048, nullptr, 0, 0);

  GemmP gm{};
  gm.X1 = catb; gm.ldx1 = 4096; gm.nc1 = 128;
  gm.Hst = catb;
  gm.Wf1 = (const float*)d_in[27]; gm.Wb1 = (const float*)d_in[27]; gm.ldw1 = 4096;
  gm.Wf2 = (const float*)d_in[27]; gm.Wb2 = (const float*)d_in[27];
  gm.bihf = nullptr; gm.bhhf = nullptr; gm.bihb = nullptr; gm.bhhb = nullptr;
  gm.gout = ws_mdn; gm.ksplit = 16; gm.totc = 128; gm.ndir = 1; gm.nW = 121; gm.ldo = 128;
  gemm_k<<<dim3(2, 4, 16), 256, 0, stream>>>(gm);

  mdn_fin<<<256, 128, 0, stream>>>(ws_mdn, 16, (const float*)d_in[28], out);
}

// Round 14
// 299.493 us; speedup vs baseline: 1.3826x; 1.3826x over previous
//
#include <hip/hip_runtime.h>

#define Bsz 256
#define Usz 64
#define CVsz 61
#define INsz 3
#define Hsz 1024
#define Gsz 4096
#define NGsz 20
#define NAGsz 10
#define IN2sz 2112

typedef __attribute__((ext_vector_type(8))) short bf16x8;
typedef __attribute__((ext_vector_type(4))) float f32x4;
typedef __attribute__((ext_vector_type(4))) unsigned int u32x4;

__device__ __forceinline__ unsigned int pk2(float x, float y) {
  unsigned int a = __float_as_uint(x), b = __float_as_uint(y);
  return ((a + 0x8000u) >> 16) | ((b + 0x8000u) & 0xffff0000u);
}
__device__ __forceinline__ unsigned short bf1(float x) {
  return (unsigned short)((__float_as_uint(x) + 0x8000u) >> 16);
}
__device__ __forceinline__ bf16x8 pkb4(f32x4 lo, f32x4 hi) {
  union { u32x4 u; bf16x8 b; } cv;
  cv.u = (u32x4){pk2(lo[0], lo[1]), pk2(lo[2], lo[3]), pk2(hi[0], hi[1]), pk2(hi[2], hi[3])};
  return cv.b;
}
__device__ __forceinline__ float sigf(float x) { return 1.f / (1.f + __expf(-x)); }

// 16B-per-lane async global->LDS. LDS dest = wave-uniform base + lane*16 (linear).
__device__ __forceinline__ void gload16(const void* g, void* l) {
  __builtin_amdgcn_global_load_lds(
      (const __attribute__((address_space(1))) unsigned int*)g,
      (__attribute__((address_space(3))) unsigned int*)l, 16, 0, 0);
}

struct GemmP {
  const unsigned short* X1; int ldx1; int nc1;   // bf16 activation part 1
  const unsigned short* Hst;                     // bf16 h-state (2 dirs), ld=Hsz
  const float* Wf1; const float* Wb1; int ldw1;  // f32 Wih per dir
  const float* Wf2; const float* Wb2;            // f32 Whh per dir, ld=Hsz
  const float* bihf; const float* bhhf; const float* bihb; const float* bhhb;
  float* gout;
  int ksplit; int totc; int ndir; int nW; int ldo;
};

// C[m][n] = sum_k A[m][k] * W[n][k] (+bias on slice 0).
// 128x128 tile, BK=32, 4 waves 2x2 (wave 64x64 = 4x4 frags, 16 MFMA/iter).
// Staging via global_load_lds (zero VGPR, whole 24KB tile in flight), LDS dbuf,
// one barrier/iter. Source-address XOR swizzle (A: slot^=(row>>1)&3, W: slot^=row&7)
// keeps LDS linear for the DMA while fragment ds_read_b128s are bank-balanced.
__global__ __launch_bounds__(256) void gemm_k(GemmP p) {
  __shared__ __align__(16) unsigned short Alds[2][128 * 32];  // bf16, 8KB each
  __shared__ __align__(16) float Wlds[2][128 * 32];           // f32, 16KB each
  int t = threadIdx.x;
  int n0 = blockIdx.x * 128, m0 = blockIdx.y * 128;
  int z = blockIdx.z;
  int d = (p.ndir == 2) ? (z & 1) : 0;
  int s = (p.ndir == 2) ? (z >> 1) : z;
  const float* Wih = d ? p.Wb1 : p.Wf1;
  const float* Whh = d ? p.Wb2 : p.Wf2;
  const unsigned short* Hx = p.Hst + (size_t)d * Bsz * Hsz;
  int c0 = (p.totc * s) / p.ksplit, c1 = (p.totc * (s + 1)) / p.ksplit;
  int wv = t >> 6, ln = t & 63;
  int wr = wv >> 1, wc = wv & 1;
  int fr = ln & 15, kg = ln >> 4;

  f32x4 acc[4][4];
#pragma unroll
  for (int i = 0; i < 4; i++)
#pragma unroll
    for (int j = 0; j < 4; j++) acc[i][j] = (f32x4){0.f, 0.f, 0.f, 0.f};

  auto STAGE = [&](int buf, int c) {
    const unsigned short* Xp; int ldx; const float* Wp; int ldw; int kx;
    if (c < p.nc1) { Xp = p.X1; ldx = p.ldx1; kx = c * 32; Wp = Wih; ldw = p.ldw1; }
    else           { Xp = Hx;   ldx = Hsz;    kx = (c - p.nc1) * 32; Wp = Whh; ldw = Hsz; }
    // A: 128 rows x 32 bf16 (64B/row, 4 lanes/row, 16 rows/instr, 2 instr/wave)
#pragma unroll
    for (int q = 0; q < 2; q++) {
      int r0 = (wv * 2 + q) * 16;
      int row = r0 + (ln >> 2);
      int ch = (ln & 3) ^ ((row >> 1) & 3);  // inverse swizzle on the SOURCE
      gload16(Xp + (size_t)(m0 + row) * ldx + kx + ch * 8, &Alds[buf][r0 * 32]);
    }
    // W: 128 rows x 32 f32 (128B/row, 8 lanes/row, 8 rows/instr, 4 instr/wave)
#pragma unroll
    for (int q = 0; q < 4; q++) {
      int r0 = (wv * 4 + q) * 8;
      int row = r0 + (ln >> 3);
      int rw = n0 + row; if (rw >= p.nW) rw = p.nW - 1;
      int ch = (ln & 7) ^ (row & 7);
      gload16(Wp + (size_t)rw * ldw + kx + ch * 4, &Wlds[buf][r0 * 32]);
    }
  };

  auto COMPUTE = [&](int buf) {
    bf16x8 av[4], bv[4];
    int gA = (fr >> 1) & 3, gW = fr & 7;
#pragma unroll
    for (int i = 0; i < 4; i++) {
      int row = wr * 64 + i * 16 + fr;
      av[i] = *(const bf16x8*)&Alds[buf][row * 32 + (kg ^ gA) * 8];
    }
#pragma unroll
    for (int j = 0; j < 4; j++) {
      int row = wc * 64 + j * 16 + fr;
      f32x4 lo = *(const f32x4*)&Wlds[buf][row * 32 + ((2 * kg) ^ gW) * 4];
      f32x4 hi = *(const f32x4*)&Wlds[buf][row * 32 + ((2 * kg + 1) ^ gW) * 4];
      bv[j] = pkb4(lo, hi);
    }
#pragma unroll
    for (int i = 0; i < 4; i++)
#pragma unroll
      for (int j = 0; j < 4; j++)
        acc[i][j] = __builtin_amdgcn_mfma_f32_16x16x32_bf16(av[i], bv[j], acc[i][j], 0, 0, 0);
  };

  STAGE(0, c0);
  __syncthreads();  // drain: tile c0 resident
  int cur = 0;
  for (int c = c0 + 1; c < c1; ++c) {
    STAGE(cur ^ 1, c);   // issue next tile (24KB in flight, no VGPRs)
    COMPUTE(cur);        // MFMA on current overlaps the loads
    __syncthreads();     // one barrier/iter: next tile landed, cur fully read
    cur ^= 1;
  }
  COMPUTE(cur);

  const float* bi = d ? p.bihb : p.bihf;
  const float* bh = d ? p.bhhb : p.bhhf;
  float* outp = p.gout + (size_t)(s * p.ndir + d) * Bsz * p.ldo;
#pragma unroll
  for (int i = 0; i < 4; i++) {
#pragma unroll
    for (int j = 0; j < 4; j++) {
      int col = n0 + wc * 64 + j * 16 + fr;
      float bias = 0.f;
      if (p.bihf && s == 0) bias = bi[col] + bh[col];
#pragma unroll
      for (int r = 0; r < 4; r++) {
        int row = m0 + wr * 64 + i * 16 + kg * 4 + r;
        outp[(size_t)row * p.ldo + col] = acc[i][j][r] + bias;
      }
    }
  }
}

__global__ __launch_bounds__(256) void prep_x1b(const float* inp, const float* oldw, unsigned short* x1b) {
  int idx = blockIdx.x * 256 + threadIdx.x;  // 256*64
  int m = idx >> 6, k = idx & 63;
  float v = (k < INsz) ? inp[m * INsz + k] : oldw[m * CVsz + (k - INsz)];
  x1b[idx] = bf1(v);
}

__global__ __launch_bounds__(256) void cvt_h(const float* h, unsigned short* hb, int n) {
  int idx = blockIdx.x * 256 + threadIdx.x;
  if (idx < n) hb[idx] = bf1(h[idx]);
}

__global__ __launch_bounds__(256) void cell_k(const float* gates, int ksplit,
    const float* cin, float* hout, float* cout,
    unsigned short* db1, int ld1, int off1, unsigned short* db2, int ld2, int off2) {
  int idx = blockIdx.x * 256 + threadIdx.x;  // [0, 2*B*H)
  int j = idx & (Hsz - 1);
  int m = (idx >> 10) & 255;
  int d = idx >> 18;
  size_t base = ((size_t)d * Bsz + m) * Gsz + j;
  float gi = 0.f, gf = 0.f, gg = 0.f, go = 0.f;
  for (int s = 0; s < ksplit; ++s) {
    const float* gp = gates + (size_t)s * 2 * Bsz * Gsz + base;
    gi += gp[0]; gf += gp[1024]; gg += gp[2048]; go += gp[3072];
  }
  float c = cin[((size_t)d * Bsz + m) * Hsz + j];
  float cn = sigf(gf) * c + sigf(gi) * tanhf(gg);
  float hn = sigf(go) * tanhf(cn);
  hout[((size_t)d * Bsz + m) * Hsz + j] = hn;
  cout[((size_t)d * Bsz + m) * Hsz + j] = cn;
  unsigned short hb = bf1(hn);
  db1[(size_t)m * ld1 + off1 + d * Hsz + j] = hb;
  if (db2) db2[(size_t)m * ld2 + off2 + d * Hsz + j] = hb;
}

// Reduce win-projection partials, compute abk/k_t/phi/win, scatter bf16 into x2b.
__global__ __launch_bounds__(128) void win_fin(const float* winp, int ks,
    const float* bwin, const float* oldk, const float* inp, const float* cvec,
    const int* tl, unsigned short* x2b, float* ophi, float* owin, float* okt) {
  int m = blockIdx.x, t = threadIdx.x, wv = t >> 6, ln = t & 63;
  __shared__ float abk[30];
  __shared__ float phis[Usz];
  __shared__ float wpart[2][CVsz];
  if (t < 30) {
    float s = bwin[t];
    for (int q = 0; q < ks; ++q) s += winp[((size_t)q * Bsz + m) * 128 + t];
    abk[t] = __expf(s);
  }
  __syncthreads();
  if (t < NAGsz) {
    float kt = oldk[m * NAGsz + t] + abk[20 + t];
    abk[20 + t] = kt;
    okt[m * NAGsz + t] = kt;
  }
  __syncthreads();
  if (t < Usz) {
    float scale = 64.f / (float)tl[0];
    float ph = 0.f;
#pragma unroll
    for (int q = 0; q < NAGsz; ++q) {
      float dk = abk[20 + q] - (float)(t + 1);
      ph += abk[q] * __expf(-abk[10 + q] * dk * dk);
    }
    ph *= scale;
    phis[t] = ph;
    ophi[m * Usz + t] = ph;
  }
  __syncthreads();
  if (ln < CVsz) {
    float w = 0.f;
    const float* cv = cvec + (size_t)m * Usz * CVsz + (size_t)wv * 32 * CVsz + ln;
#pragma unroll
    for (int u = 0; u < 32; ++u) w += phis[wv * 32 + u] * cv[u * CVsz];
    wpart[wv][ln] = w;
  }
  __syncthreads();
  if (t < CVsz) {
    float w = wpart[0][t] + wpart[1][t];
    owin[m * CVsz + t] = w;
    x2b[(size_t)m * IN2sz + 2048 + INsz + t] = bf1(w);
  }
  if (t < INsz) x2b[(size_t)m * IN2sz + 2048 + t] = bf1(inp[m * INsz + t]);
}

__global__ __launch_bounds__(128) void mdn_fin(const float* part, int ks, const float* bm, float* out) {
  int m = blockIdx.x, t = threadIdx.x;
  __shared__ float y[121];
  if (t < 121) {
    float s = bm[t];
    for (int q = 0; q < ks; ++q) s += part[((size_t)q * Bsz + m) * 128 + t];
    y[t] = s;
  }
  __syncthreads();
  if (t == 0) out[m] = sigf(y[0]);
  if (t < NGsz) {
    float mx = -1e30f;
    for (int q = 0; q < NGsz; q++) mx = fmaxf(mx, y[1 + q]);
    float se = 0.f;
    for (int q = 0; q < NGsz; q++) se += __expf(y[1 + q] - mx);
    out[256   + m * NGsz + t] = __expf(y[1 + t] - mx) / se;  // pi
    out[5376  + m * NGsz + t] = y[21 + t];                   // mu1
    out[10496 + m * NGsz + t] = y[41 + t];                   // mu2
    out[15616 + m * NGsz + t] = __expf(y[61 + t]);           // exp(s1)
    out[20736 + m * NGsz + t] = __expf(y[81 + t]);           // exp(s2)
    out[25856 + m * NGsz + t] = tanhf(y[101 + t]);           // tanh(rho)
  }
}

extern "C" void kernel_launch(void* const* d_in, const int* in_sizes, int n_in,
                              void* d_out, int out_size, void* d_ws, size_t ws_size,
                              hipStream_t stream) {
  (void)in_sizes; (void)n_in; (void)out_size;
  const float* inp  = (const float*)d_in[0];
  const float* cvec = (const float*)d_in[1];
  const float* oldk = (const float*)d_in[2];
  const float* oldw = (const float*)d_in[3];
  const float* h1   = (const float*)d_in[4];
  const float* c1   = (const float*)d_in[5];
  const float* h2   = (const float*)d_in[6];
  const float* c2   = (const float*)d_in[7];
  const int*   tl   = (const int*)d_in[8];
  float* out = (float*)d_out;
  float* ws  = (float*)d_ws;

  // fixed: mdn 524288 + winp 524288 + bf16 bufs (2654208 shorts = 1327104 floats)
  size_t fixed_f = (size_t)524288 + 524288 + 1327104;
  int ks2 = 4;
  while (ks2 > 1 && (fixed_f + (size_t)ks2 * 2 * 1048576) * 4 > ws_size) ks2 >>= 1;
  int ks1 = ks2;

  float* ws_g    = ws;                                 // ks2*2*1048576 f32 partials
  float* ws_mdn  = ws_g + (size_t)ks2 * 2 * 1048576;   // 16x256x128
  float* ws_winp = ws_mdn + 524288;                    // 16x256x128
  float* bstart  = ws_winp + 524288;
  unsigned short* x1b  = (unsigned short*)bstart;      // 16384
  unsigned short* h1b  = x1b + 16384;                  // 524288
  unsigned short* h2b  = h1b + 524288;                 // 524288
  unsigned short* x2b  = h2b + 524288;                 // 540672
  unsigned short* catb = x2b + 540672;                 // 1048576

  prep_x1b<<<64, 256, 0, stream>>>(inp, oldw, x1b);
  cvt_h<<<2048, 256, 0, stream>>>(h1, h1b, 524288);
  cvt_h<<<2048, 256, 0, stream>>>(h2, h2b, 524288);

  GemmP g1{};
  g1.X1 = x1b; g1.ldx1 = 64; g1.nc1 = 2;
  g1.Hst = h1b;
  g1.Wf1 = (const float*)d_in[9];  g1.Wb1 = (const float*)d_in[13]; g1.ldw1 = 64;
  g1.Wf2 = (const float*)d_in[10]; g1.Wb2 = (const float*)d_in[14];
  g1.bihf = (const float*)d_in[11]; g1.bhhf = (const float*)d_in[12];
  g1.bihb = (const float*)d_in[15]; g1.bhhb = (const float*)d_in[16];
  g1.gout = ws_g; g1.ksplit = ks1; g1.totc = 34; g1.ndir = 2; g1.nW = 4096; g1.ldo = 4096;
  gemm_k<<<dim3(32, 2, 2 * ks1), 256, 0, stream>>>(g1);

  cell_k<<<2048, 256, 0, stream>>>(ws_g, ks1, c1, out + 65536, out + 589824,
                                   x2b, IN2sz, 0, catb, 4096, 0);

  // win projection: A = x2b[:, :2048] (bf16), W = W_win f32 [30,2048]
  GemmP gw{};
  gw.X1 = x2b; gw.ldx1 = IN2sz; gw.nc1 = 64;
  gw.Hst = x2b;
  gw.Wf1 = (const float*)d_in[25]; gw.Wb1 = (const float*)d_in[25]; gw.ldw1 = 2048;
  gw.Wf2 = (const float*)d_in[25]; gw.Wb2 = (const float*)d_in[25];
  gw.bihf = nullptr; gw.bhhf = nullptr; gw.bihb = nullptr; gw.bhhb = nullptr;
  gw.gout = ws_winp; gw.ksplit = 16; gw.totc = 64; gw.ndir = 1; gw.nW = 30; gw.ldo = 128;
  gemm_k<<<dim3(1, 2, 16), 256, 0, stream>>>(gw);

  win_fin<<<256, 128, 0, stream>>>(ws_winp, 16, (const float*)d_in[26],
                                   oldk, inp, cvec, tl, x2b,
                                   out + 30976, out + 47360, out + 62976);

  GemmP g2{};
  g2.X1 = x2b; g2.ldx1 = IN2sz; g2.nc1 = 66;
  g2.Hst = h2b;
  g2.Wf1 = (const float*)d_in[17]; g2.Wb1 = (const float*)d_in[21]; g2.ldw1 = IN2sz;
  g2.Wf2 = (const float*)d_in[18]; g2.Wb2 = (const float*)d_in[22];
  g2.bihf = (const float*)d_in[19]; g2.bhhf = (const float*)d_in[20];
  g2.bihb = (const float*)d_in[23]; g2.bhhb = (const float*)d_in[24];
  g2.gout = ws_g; g2.ksplit = ks2; g2.totc = 98; g2.ndir = 2; g2.nW = 4096; g2.ldo = 4096;
  gemm_k<<<dim3(32, 2, 2 * ks2), 256, 0, stream>>>(g2);

  cell_k<<<2048, 256, 0, stream>>>(ws_g, ks2, c2, out + 1114112, out + 1638400,
                                   catb, 4096, 2048, nullptr, 0, 0);

  GemmP gm{};
  gm.X1 = catb; gm.ldx1 = 4096; gm.nc1 = 128;
  gm.Hst = catb;
  gm.Wf1 = (const float*)d_in[27]; gm.Wb1 = (const float*)d_in[27]; gm.ldw1 = 4096;
  gm.Wf2 = (const float*)d_in[27]; gm.Wb2 = (const float*)d_in[27];
  gm.bihf = nullptr; gm.bhhf = nullptr; gm.bihb = nullptr; gm.bhhb = nullptr;
  gm.gout = ws_mdn; gm.ksplit = 16; gm.totc = 128; gm.ndir = 1; gm.nW = 121; gm.ldo = 128;
  gemm_k<<<dim3(1, 2, 16), 256, 0, stream>>>(gm);

  mdn_fin<<<256, 128, 0, stream>>>(ws_mdn, 16, (const float*)d_in[28], out);
}